// Round 8
// baseline (476.583 us; speedup 1.0000x reference)
//
#include <hip/hip_runtime.h>
#include <math.h>

#define HIDDEN 4096
#define NEXP   128
#define TOPK   8
#define BM     64
#define BKC    64                  // K per chunk (wave does its wk-half: K=32)
#define NCHUNK (HIDDEN / BKC)      // 64
#define SS     132                 // padded stride for score rows in epilogue

typedef __attribute__((ext_vector_type(8))) short short8;  // 8 bf16 (4 VGPR)
typedef __attribute__((ext_vector_type(4))) float f32x4;   // 4 fp32  (4 VGPR)

__device__ __forceinline__ unsigned pack2(unsigned a, unsigned b) {
  return (a >> 16) | (b & 0xFFFF0000u);  // lo = top16(a), hi = top16(b)
}

// Triple bf16 split: x = hi + mid + lo + O(2^-24 x). hi/mid round-half-away.
struct Split3 { uint4 h, m, l; };
__device__ __forceinline__ Split3 split8v(f32x4 a, f32x4 b) {
  float x[8] = {a[0], a[1], a[2], a[3], b[0], b[1], b[2], b[3]};
  unsigned h[8], m[8], l[8];
#pragma unroll
  for (int j = 0; j < 8; ++j) {
    unsigned u  = __float_as_uint(x[j]);
    unsigned hb = (u + 0x8000u) & 0xFFFF0000u;
    float rh    = x[j] - __uint_as_float(hb);
    unsigned um = __float_as_uint(rh);
    unsigned mb = (um + 0x8000u) & 0xFFFF0000u;
    float rm    = rh - __uint_as_float(mb);
    h[j] = hb; m[j] = mb; l[j] = __float_as_uint(rm);
  }
  Split3 s;
  s.h = make_uint4(pack2(h[0],h[1]), pack2(h[2],h[3]), pack2(h[4],h[5]), pack2(h[6],h[7]));
  s.m = make_uint4(pack2(m[0],m[1]), pack2(m[2],m[3]), pack2(m[4],m[5]), pack2(m[6],m[7]));
  s.l = make_uint4(pack2(l[0],l[1]), pack2(l[2],l[3]), pack2(l[4],l[5]), pack2(l[6],l[7]));
  return s;
}

// ---- pre-pass: split W into 3 bf16 planes, packed in MFMA B-fragment order.
// fid = et*128 + kc (et = 16-expert tile, kc = K/32 chunk).
// wp[fid*1536 + s*512 + lane*8 ..] = W_s[et*16 + (lane&15)][kc*32 + (lane>>4)*8 ..]
__global__ __launch_bounds__(256) void pack_w_kernel(
    const float* __restrict__ w, ushort* __restrict__ wp)
{
  const int g    = blockIdx.x * 256 + threadIdx.x;  // 65536 threads
  const int lane = g & 63;
  const int fid  = g >> 6;                          // 0..1023
  const int et   = fid >> 7;
  const int kc   = fid & 127;
  const int e    = et * 16 + (lane & 15);
  const int k0   = kc * 32 + (lane >> 4) * 8;
  const f32x4 x0 = *(const f32x4*)(w + (size_t)e * HIDDEN + k0);
  const f32x4 x1 = *(const f32x4*)(w + (size_t)e * HIDDEN + k0 + 4);
  Split3 s = split8v(x0, x1);
  uint4* dst = (uint4*)wp + (size_t)fid * 3 * 64;
  dst[0 * 64 + lane] = s.h;
  dst[1 * 64 + lane] = s.m;
  dst[2 * 64 + lane] = s.l;
}

// volatile asm load into ext_vector regs: cannot be sunk/reordered vs other
// volatile asm (R4/R5 failure), and avoids HIP struct types in constraints
// (suspected R7 abort).
#define GL(dst, base, OFFSTR)                                               \
  asm volatile("global_load_dwordx4 %0, %1, off offset:" OFFSTR             \
               : "=&v"(dst) : "v"(base));

__global__ __launch_bounds__(512, 1) void router_kernel(
    const float*  __restrict__ h,     // [T, HIDDEN]
    const ushort* __restrict__ wp,    // packed split W (see pack_w_kernel)
    const float*  __restrict__ bias,  // [NEXP]
    float* __restrict__ out,          // [T*8] indices (as float) then [T*8] weights
    int T)
{
  __shared__ float Ss[BM * SS];      // epilogue only
  const int tid  = threadIdx.x;
  const int row0 = blockIdx.x * BM;

  const int wid  = tid >> 6;
  const int wn   = wid & 3;     // expert-column tile (32 experts)
  const int wk   = wid >> 2;    // K-parity half
  const int lane = tid & 63;
  const int lrow = lane & 15;
  const int lk   = lane >> 4;

  // bias loads FIRST (volatile => ordered before the asm ISSUEs below, so the
  // first counted vmcnt drains them and they never perturb later counts)
  const float bb0 = *(volatile const float*)(bias + lane);
  const float bb1 = *(volatile const float*)(bias + lane + 64);

  // Per-lane A bases: row = row0 + mi*16 + lrow, k = wk*32 + lk*8 (chunk 0)
  const float* aB0 = h + (size_t)(row0 +  0 + lrow) * HIDDEN + wk * 32 + lk * 8;
  const float* aB1 = h + (size_t)(row0 + 16 + lrow) * HIDDEN + wk * 32 + lk * 8;
  const float* aB2 = h + (size_t)(row0 + 32 + lrow) * HIDDEN + wk * 32 + lk * 8;
  const float* aB3 = h + (size_t)(row0 + 48 + lrow) * HIDDEN + wk * 32 + lk * 8;
  // Per-lane B bases (chunk 0); advance 3072 ushorts per chunk
  const ushort* bB0 = wp + (size_t)((wn * 2 + 0) * 128 + wk) * 1536 + (size_t)lane * 8;
  const ushort* bB1 = wp + (size_t)((wn * 2 + 1) * 128 + wk) * 1536 + (size_t)lane * 8;

  f32x4 acc[4][2];
#pragma unroll
  for (int i = 0; i < 4; ++i)
#pragma unroll
    for (int j = 0; j < 2; ++j) acc[i][j] = (f32x4){0.f, 0.f, 0.f, 0.f};

  f32x4  arA[4][2], arB[4][2];      // raw fp32 A, double-buffered (ext_vector)
  short8 bfA[2][3], bfB[2][3];      // packed B fragments, double-buffered

  // issue one chunk's 14 loads (8 A + 6 B), then advance bases
#define ISSUE(ar, bf)                                                       \
  GL(ar[0][0], aB0, "0")  GL(ar[0][1], aB0, "16")                           \
  GL(ar[1][0], aB1, "0")  GL(ar[1][1], aB1, "16")                           \
  GL(ar[2][0], aB2, "0")  GL(ar[2][1], aB2, "16")                           \
  GL(ar[3][0], aB3, "0")  GL(ar[3][1], aB3, "16")                           \
  GL(bf[0][0], bB0, "0")  GL(bf[0][1], bB0, "1024")  GL(bf[0][2], bB0, "2048") \
  GL(bf[1][0], bB1, "0")  GL(bf[1][1], bB1, "1024")  GL(bf[1][2], bB1, "2048") \
  aB0 += BKC; aB1 += BKC; aB2 += BKC; aB3 += BKC; bB0 += 3072; bB1 += 3072;

  // counted wait (previous chunk landed; next chunk stays in flight) + fence
  // (rule #18: sched_barrier stops VALU/MFMA hoisting above the waitcnt)
#define WAITC(NSTR)                                                         \
  asm volatile("s_waitcnt vmcnt(" NSTR ")" ::: "memory");                   \
  __builtin_amdgcn_sched_barrier(0);

#define COMPUTE(ar, bf)                                                     \
  _Pragma("unroll")                                                         \
  for (int mi = 0; mi < 4; ++mi) {                                          \
    Split3 s_ = split8v(ar[mi][0], ar[mi][1]);                              \
    short8 afh = *(short8*)&s_.h;                                           \
    short8 afm = *(short8*)&s_.m;                                           \
    short8 afl = *(short8*)&s_.l;                                           \
    __builtin_amdgcn_s_setprio(1);                                          \
    _Pragma("unroll")                                                       \
    for (int ni = 0; ni < 2; ++ni) {                                        \
      f32x4 cc = acc[mi][ni];                                               \
      cc = __builtin_amdgcn_mfma_f32_16x16x32_bf16(afh, bf[ni][0], cc, 0, 0, 0); \
      cc = __builtin_amdgcn_mfma_f32_16x16x32_bf16(afh, bf[ni][1], cc, 0, 0, 0); \
      cc = __builtin_amdgcn_mfma_f32_16x16x32_bf16(afm, bf[ni][0], cc, 0, 0, 0); \
      cc = __builtin_amdgcn_mfma_f32_16x16x32_bf16(afh, bf[ni][2], cc, 0, 0, 0); \
      cc = __builtin_amdgcn_mfma_f32_16x16x32_bf16(afl, bf[ni][0], cc, 0, 0, 0); \
      cc = __builtin_amdgcn_mfma_f32_16x16x32_bf16(afm, bf[ni][1], cc, 0, 0, 0); \
      acc[mi][ni] = cc;                                                     \
    }                                                                       \
    __builtin_amdgcn_s_setprio(0);                                          \
  }

  // ---- main loop: no LDS, no barriers; 1-chunk-deep pinned pipeline
  ISSUE(arA, bfA)                       // chunk 0 in flight
  for (int c = 0; c < NCHUNK - 2; c += 2) {
    ISSUE(arB, bfB)                     // chunk c+1
    WAITC("14")                         // chunk c landed (+ bias on 1st pass)
    COMPUTE(arA, bfA)
    ISSUE(arA, bfA)                     // chunk c+2
    WAITC("14")                         // chunk c+1 landed
    COMPUTE(arB, bfB)
  }
  ISSUE(arB, bfB)                       // chunk 63
  WAITC("14")
  COMPUTE(arA, bfA)                     // chunk 62
  WAITC("0")
  COMPUTE(arB, bfB)                     // chunk 63

#undef COMPUTE
#undef WAITC
#undef ISSUE
#undef GL

  // ---- combine wave-pair K-partials in LDS
  if (wk == 1) {
#pragma unroll
    for (int mi = 0; mi < 4; ++mi)
#pragma unroll
      for (int ni = 0; ni < 2; ++ni)
#pragma unroll
        for (int j = 0; j < 4; ++j)
          // D layout (m89): col = lane&15, row = (lane>>4)*4 + j
          Ss[(mi * 16 + lk * 4 + j) * SS + wn * 32 + ni * 16 + lrow] = acc[mi][ni][j];
  }
  __syncthreads();
  if (wk == 0) {
#pragma unroll
    for (int mi = 0; mi < 4; ++mi)
#pragma unroll
      for (int ni = 0; ni < 2; ++ni)
#pragma unroll
        for (int j = 0; j < 4; ++j) {
          const int ixs = (mi * 16 + lk * 4 + j) * SS + wn * 32 + ni * 16 + lrow;
          Ss[ixs] += acc[mi][ni][j];
        }
  }
  __syncthreads();

  // ---- top-k epilogue: wave wid handles tokens wid, wid+8, ...
  for (int t = wid; t < BM; t += 8) {
    const float lg0 = Ss[t * SS + lane];
    const float lg1 = Ss[t * SS + 64 + lane];
    const float s0 = 1.0f / (1.0f + expf(-lg0));  // raw sigmoid score
    const float s1 = 1.0f / (1.0f + expf(-lg1));
    float c0 = s0 + bb0;                          // bias-corrected, for selection
    float c1 = s1 + bb1;

    int   sel_i[TOPK];
    float sel_r[TOPK];
    float rsum = 0.0f;
#pragma unroll
    for (int j = 0; j < TOPK; ++j) {
      const bool take0 = (c0 >= c1);
      float v  = take0 ? c0 : c1;
      float rr = take0 ? s0 : s1;
      int   ii = take0 ? lane : lane + 64;
#pragma unroll
      for (int off = 32; off > 0; off >>= 1) {
        const float ov  = __shfl_xor(v, off, 64);
        const float orr = __shfl_xor(rr, off, 64);
        const int   oi  = __shfl_xor(ii, off, 64);
        if (ov > v || (ov == v && oi < ii)) { v = ov; rr = orr; ii = oi; }
      }
      sel_i[j] = ii;
      sel_r[j] = rr;
      rsum += rr;
      if (ii == lane)      c0 = -__builtin_inff();
      if (ii == lane + 64) c1 = -__builtin_inff();
    }
    if (lane == 0) {
      const float inv = 1.0f / (rsum + 1e-20f);
      const size_t tok = (size_t)(row0 + t);
#pragma unroll
      for (int j = 0; j < TOPK; ++j) {
        out[tok * TOPK + j]                    = (float)sel_i[j];
        out[(size_t)T * TOPK + tok * TOPK + j] = sel_r[j] * inv;
      }
    }
  }
}

extern "C" void kernel_launch(void* const* d_in, const int* in_sizes, int n_in,
                              void* d_out, int out_size, void* d_ws, size_t ws_size,
                              hipStream_t stream) {
  const float* h    = (const float*)d_in[0];
  const float* w    = (const float*)d_in[1];
  const float* bias = (const float*)d_in[2];
  float* out = (float*)d_out;
  ushort* wp = (ushort*)d_ws;          // needs 1024*1536*2 B = 3 MiB
  const int T = in_sizes[0] / HIDDEN;  // 16384

  hipLaunchKernelGGL(pack_w_kernel, dim3(256), dim3(256), 0, stream, w, wp);

  dim3 grid(T / BM);   // 256 blocks -> 1 per CU
  dim3 block(512);     // 8 waves: 4 expert tiles x 2 K-halves
  hipLaunchKernelGGL(router_kernel, grid, block, 0, stream, h, wp, bias, out, T);
}